// Round 7
// baseline (2252.135 us; speedup 1.0000x reference)
//
#include <hip/hip_runtime.h>

#define MDIM 8192
#define NDIM 4096
#define KDIM 4096
#define BM 256
#define BN 256
#define BK 128

typedef int v4i __attribute__((ext_vector_type(4)));
typedef int v16i __attribute__((ext_vector_type(16)));

__device__ __forceinline__ unsigned pack4(int x, int y, int z, int w) {
    return (unsigned)(x & 0xff) | ((unsigned)(y & 0xff) << 8) |
           ((unsigned)(z & 0xff) << 16) | ((unsigned)w << 24);
}

// ---- pass 1: int32 -> packed int8, pre-tiled ----
// A: [mtile 0..31][kiter 0..31][kb 0..7][row 0..255] 16B granules (2048/subtile)
// B: [ntile 0..15][kiter 0..31][h 0..31][lane 0..63] 16B granules (2048/subtile)
//    h = wc*8 + nt*4 + ks; lane holds B[row=wc*64+nt*32+(lane&31)]
//    [k=(2ks+(lane>>5))*16 ..+15] == exact MFMA B-fragment order per wave.
// Transpose via padded LDS (pitch 33 dwords); reads and writes coalesced.
__global__ __launch_bounds__(256) void pack_tiled(const int* __restrict__ x,
                                                  const int* __restrict__ w,
                                                  uint4* __restrict__ xp,
                                                  uint4* __restrict__ wp) {
    __shared__ unsigned lds32[256 * 33];
    const int wg  = blockIdx.x;
    const int tid = threadIdx.x;
    const int kq   = tid & 31;
    const int rsub = tid >> 5;

    if (wg < 1024) {  // A subtiles: 256 rows x 128 k
        const int mtile = wg >> 5, kiter = wg & 31;
        const int* base = x + (size_t)(mtile * 256) * KDIM + kiter * 128;
#pragma unroll
        for (int it = 0; it < 32; ++it) {
            const int row = it * 8 + rsub;
            int4 v = *(const int4*)(base + (size_t)row * KDIM + kq * 4);
            lds32[row * 33 + kq] = pack4(v.x, v.y, v.z, v.w);
        }
        __syncthreads();
        uint4* dst = xp + (size_t)(mtile * 32 + kiter) * 2048;
#pragma unroll
        for (int it = 0; it < 8; ++it) {
            const int g = it * 256 + tid;           // 0..2047
            const int kb = g >> 8, row = g & 255;
            const unsigned* p = &lds32[row * 33 + kb * 4];
            uint4 o;
            o.x = p[0]; o.y = p[1]; o.z = p[2]; o.w = p[3];
            dst[g] = o;
        }
    } else {  // B subtiles: 256 rows x 128 k
        const int ntile = (wg - 1024) >> 5, kiter = wg & 31;
        const int* base = w + (size_t)(ntile * 256) * KDIM + kiter * 128;
#pragma unroll
        for (int it = 0; it < 32; ++it) {
            const int row = it * 8 + rsub;
            int4 v = *(const int4*)(base + (size_t)row * KDIM + kq * 4);
            lds32[row * 33 + kq] = pack4(v.x, v.y, v.z, v.w);
        }
        __syncthreads();
        uint4* dst = wp + (size_t)(ntile * 32 + kiter) * 2048;
#pragma unroll
        for (int it = 0; it < 8; ++it) {
            const int g  = it * 256 + tid;          // 0..2047
            const int ln = g & 63, h = g >> 6;      // h 0..31
            const int wc2 = h >> 3, nt = (h >> 2) & 1, ks = h & 3;
            const int row = wc2 * 64 + nt * 32 + (ln & 31);
            const int kb  = 2 * ks + (ln >> 5);
            const unsigned* p = &lds32[row * 33 + kb * 4];
            uint4 o;
            o.x = p[0]; o.y = p[1]; o.z = p[2]; o.w = p[3];
            dst[g] = o;
        }
    }
}

// ---- pass 2: int8 GEMM, out = x @ W^T ----
// Block 256x256, BK=128, 512 threads = 8 waves in 2(wr) x 4(wc); each wave
// 128x64 via 4x2 mfma_i32_32x32x32_i8 over 4 ks. Pipelined 1-barrier K-loop:
// A double-buffered in LDS (2x32KB, kb-major, conflict-free b128: contiguous
// 512B half-wave segments); B fragments double-buffered in VGPRs (fragment-
// ordered packed array, coalesced 1KB loads, L2/L3-resident). Inside compute,
// A fragments are register double-buffered across ks so ds_reads for ks+1
// issue before the MFMAs of ks (LDS latency hidden under MFMA).
template <bool PACKED>
__global__ __launch_bounds__(512, 4) void gemm_i8(const char* __restrict__ Ap,
                                                  const char* __restrict__ Bp,
                                                  const int* __restrict__ A32,
                                                  const int* __restrict__ B32,
                                                  const _Float16* __restrict__ bias,
                                                  _Float16* __restrict__ out) {
    __shared__ char lds[65536];

    const int tid  = threadIdx.x;
    const int lane = tid & 63;
    const int wave = tid >> 6;     // 0..7
    const int bm0 = blockIdx.y * BM;
    const int bn0 = blockIdx.x * BN;
    const int wr  = wave >> 2;     // 0..1 (M)
    const int wc  = wave & 3;      // 0..3 (N)
    const int l31 = lane & 31;
    const int kg  = lane >> 5;

    // A panel: subtile = [kb 0..7][row 0..255] granules; chunk c (0..31) =
    // granules c*64 + lane -> kb=c>>2, row=(c&3)*64+lane. 8 waves, 4 chunks each.
    const char* apan = Ap + (size_t)blockIdx.y * (BM * KDIM) + lane * 16;
    // B panel: wave's 8 fragment chunks at + (wc*8 + nt*4 + ks)*1024.
    const char* bpan = Bp + (size_t)blockIdx.x * (BN * KDIM) + wc * 8192 + lane * 16;

    int abase[4];
#pragma unroll
    for (int mt = 0; mt < 4; ++mt)
        abase[mt] = kg * 4096 + (wr * 128 + mt * 32 + l31) * 16;

    v16i acc[4][2];
#pragma unroll
    for (int mt = 0; mt < 4; ++mt)
#pragma unroll
        for (int nt = 0; nt < 2; ++nt)
#pragma unroll
            for (int i = 0; i < 16; ++i) acc[mt][nt][i] = 0;

    auto issueA = [&](char* buf, const char* pan) {
#pragma unroll
        for (int r = 0; r < 4; ++r) {
            const int c = r * 8 + wave;
            __builtin_amdgcn_global_load_lds(
                (__attribute__((address_space(1))) void*)(pan + c * 1024),
                (__attribute__((address_space(3))) void*)(buf + c * 1024), 16, 0, 0);
        }
    };
    auto loadB = [&](v4i (&bf)[2][4], const char* pan) {
#pragma unroll
        for (int nt = 0; nt < 2; ++nt)
#pragma unroll
            for (int ks = 0; ks < 4; ++ks)
                bf[nt][ks] = *(const v4i*)(pan + (nt * 4 + ks) * 1024);
    };
    auto compute = [&](const char* buf, const v4i (&bf)[2][4]) {
        v4i af[2][4];
#pragma unroll
        for (int mt = 0; mt < 4; ++mt)
            af[0][mt] = *(const v4i*)(buf + abase[mt]);
#pragma unroll
        for (int ks = 0; ks < 4; ++ks) {
            if (ks < 3) {
#pragma unroll
                for (int mt = 0; mt < 4; ++mt)
                    af[(ks + 1) & 1][mt] =
                        *(const v4i*)(buf + abase[mt] + (ks + 1) * 8192);
            }
#pragma unroll
            for (int mt = 0; mt < 4; ++mt)
#pragma unroll
                for (int nt = 0; nt < 2; ++nt)
                    acc[mt][nt] = __builtin_amdgcn_mfma_i32_32x32x32_i8(
                        af[ks & 1][mt], bf[nt][ks], acc[mt][nt], 0, 0, 0);
        }
    };

    if constexpr (PACKED) {
        v4i bf0[2][4], bf1[2][4];
        issueA(lds, apan);
        apan += BM * BK;
        loadB(bf0, bpan);
        bpan += BN * BK;
#pragma unroll 1
        for (int p = 0; p < 15; ++p) {
            __syncthreads();            // drains A(2p) DMA (issued last stage)
            issueA(lds + 32768, apan);  // prefetch iter 2p+1
            apan += BM * BK;
            loadB(bf1, bpan);
            bpan += BN * BK;
            compute(lds, bf0);          // iter 2p
            __syncthreads();
            issueA(lds, apan);          // prefetch iter 2p+2
            apan += BM * BK;
            loadB(bf0, bpan);
            bpan += BN * BK;
            compute(lds + 32768, bf1);  // iter 2p+1
        }
        __syncthreads();
        issueA(lds + 32768, apan);      // prefetch iter 31
        loadB(bf1, bpan);
        compute(lds, bf0);              // iter 30
        __syncthreads();
        compute(lds + 32768, bf1);      // iter 31
    } else {
        // fallback: non-pipelined, pack in regs from int32 (correctness path)
        int aoffs[4];
#pragma unroll
        for (int r = 0; r < 4; ++r) {
            const int c = r * 8 + wave;
            aoffs[r] = (bm0 + (c & 3) * 64 + lane) * KDIM + (c >> 2) * 16;
        }
        for (int k0 = 0; k0 < KDIM; k0 += BK) {
            v4i bfx[2][4];
#pragma unroll
            for (int r = 0; r < 4; ++r) {
                const int c = r * 8 + wave;
                const int4* s = (const int4*)(A32 + (size_t)aoffs[r]);
                int4 v0 = s[0], v1 = s[1], v2 = s[2], v3 = s[3];
                uint4 pk;
                pk.x = pack4(v0.x, v0.y, v0.z, v0.w);
                pk.y = pack4(v1.x, v1.y, v1.z, v1.w);
                pk.z = pack4(v2.x, v2.y, v2.z, v2.w);
                pk.w = pack4(v3.x, v3.y, v3.z, v3.w);
                *(uint4*)(lds + c * 1024 + lane * 16) = pk;
                aoffs[r] += BK;
            }
#pragma unroll
            for (int nt = 0; nt < 2; ++nt)
#pragma unroll
                for (int ks = 0; ks < 4; ++ks) {
                    const int* s = B32 + (size_t)(bn0 + wc * 64 + nt * 32 + l31) * KDIM
                                   + k0 + (2 * ks + kg) * 16;
                    int4 v0 = ((const int4*)s)[0], v1 = ((const int4*)s)[1];
                    int4 v2 = ((const int4*)s)[2], v3 = ((const int4*)s)[3];
                    bfx[nt][ks][0] = (int)pack4(v0.x, v0.y, v0.z, v0.w);
                    bfx[nt][ks][1] = (int)pack4(v1.x, v1.y, v1.z, v1.w);
                    bfx[nt][ks][2] = (int)pack4(v2.x, v2.y, v2.z, v2.w);
                    bfx[nt][ks][3] = (int)pack4(v3.x, v3.y, v3.z, v3.w);
                }
            __syncthreads();
            compute(lds, bfx);
            __syncthreads();
        }
    }

    // epilogue: int32 -> fp16 (exact; overflow -> inf matches ref), + bias.
    // C/D layout: col=lane&31, row=(reg&3)+8*(reg>>2)+4*(lane>>5)
    const _Float16 bv0 = bias[bn0 + wc * 64 + l31];
    const _Float16 bv1 = bias[bn0 + wc * 64 + 32 + l31];
#pragma unroll
    for (int mt = 0; mt < 4; ++mt) {
#pragma unroll
        for (int nt = 0; nt < 2; ++nt) {
            const int gcol = bn0 + wc * 64 + nt * 32 + l31;
            const _Float16 bb = nt ? bv1 : bv0;
#pragma unroll
            for (int r = 0; r < 16; ++r) {
                const int rit  = (r & 3) + 8 * (r >> 2) + 4 * kg;
                const int grow = bm0 + wr * 128 + mt * 32 + rit;
                _Float16 h = (_Float16)(float)acc[mt][nt][r] + bb;
                out[(size_t)grow * NDIM + gcol] = h;
            }
        }
    }
}

extern "C" void kernel_launch(void* const* d_in, const int* in_sizes, int n_in,
                              void* d_out, int out_size, void* d_ws, size_t ws_size,
                              hipStream_t stream) {
    const int* x = (const int*)d_in[0];
    const int* w = (const int*)d_in[1];
    const _Float16* bias = (const _Float16*)d_in[2];
    _Float16* out = (_Float16*)d_out;

    const size_t xbytes = (size_t)MDIM * KDIM;  // packed int8 bytes
    const size_t wbytes = (size_t)NDIM * KDIM;

    if (ws_size >= xbytes + wbytes) {
        char* xp = (char*)d_ws;
        char* wp = xp + xbytes;
        pack_tiled<<<1536, 256, 0, stream>>>(x, w, (uint4*)xp, (uint4*)wp);
        gemm_i8<true><<<dim3(NDIM / BN, MDIM / BM), 512, 0, stream>>>(
            xp, wp, nullptr, nullptr, bias, out);
    } else {
        gemm_i8<false><<<dim3(NDIM / BN, MDIM / BM), 512, 0, stream>>>(
            nullptr, nullptr, x, w, bias, out);
    }
}

// Round 8
// 390.512 us; speedup vs baseline: 5.7671x; 5.7671x over previous
//
#include <hip/hip_runtime.h>

#define MDIM 8192
#define NDIM 4096
#define KDIM 4096
#define BM 256
#define BN 256
#define BK 128

typedef int v4i __attribute__((ext_vector_type(4)));
typedef int v16i __attribute__((ext_vector_type(16)));

__device__ __forceinline__ unsigned pack4(int x, int y, int z, int w) {
    return (unsigned)(x & 0xff) | ((unsigned)(y & 0xff) << 8) |
           ((unsigned)(z & 0xff) << 16) | ((unsigned)w << 24);
}

// ---- pass 1: int32 -> packed int8, pre-tiled ----
// A: [mtile 0..31][kiter 0..31][kb 0..7][row 0..255] 16B granules (2048/subtile)
// B: [ntile 0..15][kiter 0..31][h 0..31][lane 0..63] 16B granules (2048/subtile)
//    h = wc*8 + nt*4 + ks; lane holds B[row=wc*64+nt*32+(lane&31)]
//    [k=(2ks+(lane>>5))*16 ..+15] == exact MFMA B-fragment order per wave.
// Transpose via padded LDS (pitch 33 dwords); reads and writes coalesced.
__global__ __launch_bounds__(256) void pack_tiled(const int* __restrict__ x,
                                                  const int* __restrict__ w,
                                                  uint4* __restrict__ xp,
                                                  uint4* __restrict__ wp) {
    __shared__ unsigned lds32[256 * 33];
    const int wg  = blockIdx.x;
    const int tid = threadIdx.x;
    const int kq   = tid & 31;
    const int rsub = tid >> 5;

    if (wg < 1024) {  // A subtiles: 256 rows x 128 k
        const int mtile = wg >> 5, kiter = wg & 31;
        const int* base = x + (size_t)(mtile * 256) * KDIM + kiter * 128;
#pragma unroll
        for (int it = 0; it < 32; ++it) {
            const int row = it * 8 + rsub;
            int4 v = *(const int4*)(base + (size_t)row * KDIM + kq * 4);
            lds32[row * 33 + kq] = pack4(v.x, v.y, v.z, v.w);
        }
        __syncthreads();
        uint4* dst = xp + (size_t)(mtile * 32 + kiter) * 2048;
#pragma unroll
        for (int it = 0; it < 8; ++it) {
            const int g = it * 256 + tid;           // 0..2047
            const int kb = g >> 8, row = g & 255;
            const unsigned* p = &lds32[row * 33 + kb * 4];
            uint4 o;
            o.x = p[0]; o.y = p[1]; o.z = p[2]; o.w = p[3];
            dst[g] = o;
        }
    } else {  // B subtiles: 256 rows x 128 k
        const int ntile = (wg - 1024) >> 5, kiter = wg & 31;
        const int* base = w + (size_t)(ntile * 256) * KDIM + kiter * 128;
#pragma unroll
        for (int it = 0; it < 32; ++it) {
            const int row = it * 8 + rsub;
            int4 v = *(const int4*)(base + (size_t)row * KDIM + kq * 4);
            lds32[row * 33 + kq] = pack4(v.x, v.y, v.z, v.w);
        }
        __syncthreads();
        uint4* dst = wp + (size_t)(ntile * 32 + kiter) * 2048;
#pragma unroll
        for (int it = 0; it < 8; ++it) {
            const int g  = it * 256 + tid;          // 0..2047
            const int ln = g & 63, h = g >> 6;      // h 0..31
            const int wc2 = h >> 3, nt = (h >> 2) & 1, ks = h & 3;
            const int row = wc2 * 64 + nt * 32 + (ln & 31);
            const int kb  = 2 * ks + (ln >> 5);
            const unsigned* p = &lds32[row * 33 + kb * 4];
            uint4 o;
            o.x = p[0]; o.y = p[1]; o.z = p[2]; o.w = p[3];
            dst[g] = o;
        }
    }
}

// ---- pass 2: int8 GEMM, out = x @ W^T ----
// Block 256x256, BK=128, 512 threads = 8 waves in 2(wr) x 4(wc); each wave
// 128x64 via 4x2 mfma_i32_32x32x32_i8 over 4 ks. Pipelined 1-barrier K-loop:
// A double-buffered in LDS (2x32KB, kb-major, conflict-free b128: contiguous
// 512B half-wave segments); B fragments double-buffered in VGPRs (fragment-
// ordered packed array, coalesced 1KB loads, L2/L3-resident).
// __launch_bounds__(512, 2): acc(128)+Bdbuf(64)+misc needs ~235 regs/wave;
// 2 waves/EU keeps the 256-reg budget -- (512,4) caused a catastrophic
// spill-to-scratch regression (R7: 10 GB HBM traffic, 15x slowdown).
template <bool PACKED>
__global__ __launch_bounds__(512, 2) void gemm_i8(const char* __restrict__ Ap,
                                                  const char* __restrict__ Bp,
                                                  const int* __restrict__ A32,
                                                  const int* __restrict__ B32,
                                                  const _Float16* __restrict__ bias,
                                                  _Float16* __restrict__ out) {
    __shared__ char lds[65536];

    const int tid  = threadIdx.x;
    const int lane = tid & 63;
    const int wave = tid >> 6;     // 0..7
    const int bm0 = blockIdx.y * BM;
    const int bn0 = blockIdx.x * BN;
    const int wr  = wave >> 2;     // 0..1 (M)
    const int wc  = wave & 3;      // 0..3 (N)
    const int l31 = lane & 31;
    const int kg  = lane >> 5;

    // A panel: chunk c (0..31) = granules c*64+lane -> kb=c>>2, row=(c&3)*64+lane.
    const char* apan = Ap + (size_t)blockIdx.y * (BM * KDIM) + lane * 16;
    // B panel: wave's 8 fragment chunks at + (wc*8 + nt*4 + ks)*1024.
    const char* bpan = Bp + (size_t)blockIdx.x * (BN * KDIM) + wc * 8192 + lane * 16;

    int abase[4];
#pragma unroll
    for (int mt = 0; mt < 4; ++mt)
        abase[mt] = kg * 4096 + (wr * 128 + mt * 32 + l31) * 16;

    v16i acc[4][2];
#pragma unroll
    for (int mt = 0; mt < 4; ++mt)
#pragma unroll
        for (int nt = 0; nt < 2; ++nt)
#pragma unroll
            for (int i = 0; i < 16; ++i) acc[mt][nt][i] = 0;

    auto issueA = [&](char* buf, const char* pan) {
#pragma unroll
        for (int r = 0; r < 4; ++r) {
            const int c = r * 8 + wave;
            __builtin_amdgcn_global_load_lds(
                (__attribute__((address_space(1))) void*)(pan + c * 1024),
                (__attribute__((address_space(3))) void*)(buf + c * 1024), 16, 0, 0);
        }
    };
    auto loadB = [&](v4i (&bf)[2][4], const char* pan) {
#pragma unroll
        for (int nt = 0; nt < 2; ++nt)
#pragma unroll
            for (int ks = 0; ks < 4; ++ks)
                bf[nt][ks] = *(const v4i*)(pan + (nt * 4 + ks) * 1024);
    };
    auto compute = [&](const char* buf, const v4i (&bf)[2][4]) {
#pragma unroll
        for (int ks = 0; ks < 4; ++ks) {
            v4i af[4];
#pragma unroll
            for (int mt = 0; mt < 4; ++mt)
                af[mt] = *(const v4i*)(buf + abase[mt] + ks * 8192);
#pragma unroll
            for (int mt = 0; mt < 4; ++mt)
#pragma unroll
                for (int nt = 0; nt < 2; ++nt)
                    acc[mt][nt] = __builtin_amdgcn_mfma_i32_32x32x32_i8(
                        af[mt], bf[nt][ks], acc[mt][nt], 0, 0, 0);
        }
    };

    if constexpr (PACKED) {
        v4i bf0[2][4], bf1[2][4];
        issueA(lds, apan);
        apan += BM * BK;
        loadB(bf0, bpan);
        bpan += BN * BK;
#pragma unroll 1
        for (int p = 0; p < 15; ++p) {
            __syncthreads();            // drains A(2p) DMA (issued last stage)
            issueA(lds + 32768, apan);  // prefetch iter 2p+1
            apan += BM * BK;
            loadB(bf1, bpan);
            bpan += BN * BK;
            compute(lds, bf0);          // iter 2p
            __syncthreads();
            issueA(lds, apan);          // prefetch iter 2p+2
            apan += BM * BK;
            loadB(bf0, bpan);
            bpan += BN * BK;
            compute(lds + 32768, bf1);  // iter 2p+1
        }
        __syncthreads();
        issueA(lds + 32768, apan);      // prefetch iter 31
        loadB(bf1, bpan);
        compute(lds, bf0);              // iter 30
        __syncthreads();
        compute(lds + 32768, bf1);      // iter 31
    } else {
        // fallback: non-pipelined, pack in regs from int32 (correctness path)
        int aoffs[4];
#pragma unroll
        for (int r = 0; r < 4; ++r) {
            const int c = r * 8 + wave;
            aoffs[r] = (bm0 + (c & 3) * 64 + lane) * KDIM + (c >> 2) * 16;
        }
        for (int k0 = 0; k0 < KDIM; k0 += BK) {
            v4i bfx[2][4];
#pragma unroll
            for (int r = 0; r < 4; ++r) {
                const int c = r * 8 + wave;
                const int4* s = (const int4*)(A32 + (size_t)aoffs[r]);
                int4 v0 = s[0], v1 = s[1], v2 = s[2], v3 = s[3];
                uint4 pk;
                pk.x = pack4(v0.x, v0.y, v0.z, v0.w);
                pk.y = pack4(v1.x, v1.y, v1.z, v1.w);
                pk.z = pack4(v2.x, v2.y, v2.z, v2.w);
                pk.w = pack4(v3.x, v3.y, v3.z, v3.w);
                *(uint4*)(lds + c * 1024 + lane * 16) = pk;
                aoffs[r] += BK;
            }
#pragma unroll
            for (int nt = 0; nt < 2; ++nt)
#pragma unroll
                for (int ks = 0; ks < 4; ++ks) {
                    const int* s = B32 + (size_t)(bn0 + wc * 64 + nt * 32 + l31) * KDIM
                                   + k0 + (2 * ks + kg) * 16;
                    int4 v0 = ((const int4*)s)[0], v1 = ((const int4*)s)[1];
                    int4 v2 = ((const int4*)s)[2], v3 = ((const int4*)s)[3];
                    bfx[nt][ks][0] = (int)pack4(v0.x, v0.y, v0.z, v0.w);
                    bfx[nt][ks][1] = (int)pack4(v1.x, v1.y, v1.z, v1.w);
                    bfx[nt][ks][2] = (int)pack4(v2.x, v2.y, v2.z, v2.w);
                    bfx[nt][ks][3] = (int)pack4(v3.x, v3.y, v3.z, v3.w);
                }
            __syncthreads();
            compute(lds, bfx);
            __syncthreads();
        }
    }

    // epilogue: int32 -> fp16 (exact; overflow -> inf matches ref), + bias.
    // C/D layout: col=lane&31, row=(reg&3)+8*(reg>>2)+4*(lane>>5)
    const _Float16 bv0 = bias[bn0 + wc * 64 + l31];
    const _Float16 bv1 = bias[bn0 + wc * 64 + 32 + l31];
#pragma unroll
    for (int mt = 0; mt < 4; ++mt) {
#pragma unroll
        for (int nt = 0; nt < 2; ++nt) {
            const int gcol = bn0 + wc * 64 + nt * 32 + l31;
            const _Float16 bb = nt ? bv1 : bv0;
#pragma unroll
            for (int r = 0; r < 16; ++r) {
                const int rit  = (r & 3) + 8 * (r >> 2) + 4 * kg;
                const int grow = bm0 + wr * 128 + mt * 32 + rit;
                _Float16 h = (_Float16)(float)acc[mt][nt][r] + bb;
                out[(size_t)grow * NDIM + gcol] = h;
            }
        }
    }
}

extern "C" void kernel_launch(void* const* d_in, const int* in_sizes, int n_in,
                              void* d_out, int out_size, void* d_ws, size_t ws_size,
                              hipStream_t stream) {
    const int* x = (const int*)d_in[0];
    const int* w = (const int*)d_in[1];
    const _Float16* bias = (const _Float16*)d_in[2];
    _Float16* out = (_Float16*)d_out;

    const size_t xbytes = (size_t)MDIM * KDIM;  // packed int8 bytes
    const size_t wbytes = (size_t)NDIM * KDIM;

    if (ws_size >= xbytes + wbytes) {
        char* xp = (char*)d_ws;
        char* wp = xp + xbytes;
        pack_tiled<<<1536, 256, 0, stream>>>(x, w, (uint4*)xp, (uint4*)wp);
        gemm_i8<true><<<dim3(NDIM / BN, MDIM / BM), 512, 0, stream>>>(
            xp, wp, nullptr, nullptr, bias, out);
    } else {
        gemm_i8<false><<<dim3(NDIM / BN, MDIM / BM), 512, 0, stream>>>(
            nullptr, nullptr, x, w, bias, out);
    }
}